// Round 2
// baseline (481.296 us; speedup 1.0000x reference)
//
#include <hip/hip_runtime.h>
#include <hip/hip_bf16.h>

// Causal flash attention fwd. B=2,H=16,S=2048,D=128, fp32 io, bf16 MFMA.
// R2: S^T trick (softmax along regs, P via bpermute), reg-prefetch pipeline,
// conflict-free Vt staging swizzle. LDS 32KB, target 3 blocks/CU.
constexpr int Bb = 2, Hh = 16, Ss = 2048, Dd = 128;
constexpr int BM = 64, BN = 64;
constexpr int NQT = Ss / BM;
constexpr float SCALE = 0.088388347648318447f;   // 1/sqrt(128)

typedef __attribute__((ext_vector_type(8))) short bf16x8;
typedef __attribute__((ext_vector_type(4))) short short4v;
typedef __attribute__((ext_vector_type(4))) float f32x4;
typedef __attribute__((ext_vector_type(4))) int int4v;

__device__ __forceinline__ unsigned bfbits(float f) {
  union { float f; unsigned u; } v; v.f = f;
  return v.u + 0x7FFFu + ((v.u >> 16) & 1u);     // RNE; bf16 = bits[31:16]
}
__device__ __forceinline__ short f2bf(float f) { return (short)(bfbits(f) >> 16); }
__device__ __forceinline__ unsigned packbf(float lo, float hi) {
  return (bfbits(lo) >> 16) | (bfbits(hi) & 0xFFFF0000u);
}

__global__ __launch_bounds__(256, 3)
void fa_fwd_kernel(const float* __restrict__ q, const float* __restrict__ k,
                   const float* __restrict__ v, float* __restrict__ out) {
  // K tile row-major bf16: row=256B (16x16B blocks), swizzle block^(key&15)
  __shared__ __align__(16) char Klds[BN * 256];    // 16 KB
  // V tile transposed Vt[d][key]: row=128B (8x16B blocks), swizzle block^((d^(d>>3))&7)
  __shared__ __align__(16) char Vlds[Dd * 128];    // 16 KB

  const int tid = threadIdx.x;
  const int wave = tid >> 6, lane = tid & 63, quad = lane >> 4, l16 = lane & 15;
  const int bid = blockIdx.x;
  const int bh = bid & 31;
  const int qt = (NQT - 1) - (bid >> 5);           // heavy tiles first

  const float* qb = q + (size_t)bh * Ss * Dd;
  const float* kb = k + (size_t)bh * Ss * Dd;
  const float* vb = v + (size_t)bh * Ss * Dd;

  // ---- Q fragments (scale folded). Lane holds Q[qrow=wave*16+l16][d=32ks+8quad+j]
  bf16x8 qf[4];
  {
    const float* qr = qb + (size_t)(qt * BM + wave * 16 + l16) * Dd + quad * 8;
    #pragma unroll
    for (int ks = 0; ks < 4; ++ks) {
      const float* p = qr + ks * 32;
      float4 a = *(const float4*)p, b = *(const float4*)(p + 4);
      bf16x8 t;
      t[0]=f2bf(a.x*SCALE); t[1]=f2bf(a.y*SCALE); t[2]=f2bf(a.z*SCALE); t[3]=f2bf(a.w*SCALE);
      t[4]=f2bf(b.x*SCALE); t[5]=f2bf(b.y*SCALE); t[6]=f2bf(b.z*SCALE); t[7]=f2bf(b.w*SCALE);
      qf[ks] = t;
    }
  }

  // staging geometry (constant per thread)
  const int krow0 = tid >> 5;             // K row: +8i
  const int kd0   = (tid & 31) * 4;       // K col (fp32)
  const int kblk  = kd0 >> 3;
  const int koff  = (kd0 & 4) << 1;
  const int vdq   = tid & 31;             // V d-quad
  const int vkq0  = tid >> 5;             // V key-quad: +8i

  float4 kreg[8], vreg[8];                // prefetch registers (next tile)

  auto load_tiles = [&](int kt) {
    const float* Kg = kb + (size_t)(kt * BN) * Dd;
    #pragma unroll
    for (int i = 0; i < 8; ++i)
      kreg[i] = *(const float4*)(Kg + (size_t)(krow0 + 8 * i) * Dd + kd0);
    const float* Vg = vb + (size_t)(kt * BN) * Dd;
    #pragma unroll
    for (int i = 0; i < 2; ++i) {
      int k0 = (vkq0 + 8 * i) * 4;
      #pragma unroll
      for (int r = 0; r < 4; ++r)
        vreg[i * 4 + r] = *(const float4*)(Vg + (size_t)(k0 + r) * Dd + vdq * 4);
    }
  };

  auto stage_tiles = [&]() {
    #pragma unroll
    for (int i = 0; i < 8; ++i) {
      int key = krow0 + 8 * i;
      int bswz = kblk ^ (key & 15);
      float4 f = kreg[i];
      short4v h = { f2bf(f.x), f2bf(f.y), f2bf(f.z), f2bf(f.w) };
      *(short4v*)(Klds + key * 256 + bswz * 16 + koff) = h;
    }
    #pragma unroll
    for (int i = 0; i < 2; ++i) {
      int k0 = (vkq0 + 8 * i) * 4;
      int blk = k0 >> 3;
      int off = (k0 & 4) << 1;
      const float* a0 = (const float*)&vreg[i * 4 + 0];
      const float* a1 = (const float*)&vreg[i * 4 + 1];
      const float* a2 = (const float*)&vreg[i * 4 + 2];
      const float* a3 = (const float*)&vreg[i * 4 + 3];
      #pragma unroll
      for (int j = 0; j < 4; ++j) {
        int d = vdq * 4 + j;
        int f7 = (d ^ (d >> 3)) & 7;
        int bswz = blk ^ f7;
        short4v h = { f2bf(a0[j]), f2bf(a1[j]), f2bf(a2[j]), f2bf(a3[j]) };
        *(short4v*)(Vlds + d * 128 + bswz * 16 + off) = h;
      }
    }
  };

  f32x4 o[8];
  #pragma unroll
  for (int i = 0; i < 8; ++i) o[i] = (f32x4)(0.0f);
  float mrow = -3.0e38f, lrow = 0.0f;     // per-lane scalars: qrow = wave*16+l16

  load_tiles(0);
  stage_tiles();

  const int hi2 = quad >> 1;
  const int srcbase = (l16 + 32 * (quad & 1)) * 4;   // bpermute byte index base

  for (int kt = 0; kt <= qt; ++kt) {
    __syncthreads();                       // tile kt visible in LDS
    const bool more = kt < qt;
    if (more) load_tiles(kt + 1);          // issue prefetch, no wait

    // ---- S^T = K Q^T : acc[nt][r] = S[qrow=l16][key=nt*16+quad*4+r]
    f32x4 acc[4];
    #pragma unroll
    for (int nt = 0; nt < 4; ++nt) acc[nt] = (f32x4)(0.0f);
    #pragma unroll
    for (int ks = 0; ks < 4; ++ks) {
      #pragma unroll
      for (int nt = 0; nt < 4; ++nt) {
        int row = nt * 16 + l16;
        int bswz = (ks * 4 + quad) ^ l16;
        bf16x8 kf = *(const bf16x8*)(Klds + row * 256 + bswz * 16);
        acc[nt] = __builtin_amdgcn_mfma_f32_16x16x32_bf16(kf, qf[ks], acc[nt], 0, 0, 0);
      }
    }

    // ---- causal mask on diagonal tile
    if (kt == qt) {
      #pragma unroll
      for (int nt = 0; nt < 4; ++nt)
        #pragma unroll
        for (int r = 0; r < 4; ++r)
          if (nt * 16 + quad * 4 + r > wave * 16 + l16) acc[nt][r] = -1.0e30f;
    }

    // ---- online softmax: row lives along regs; reduce across 4 quad-lanes
    float mx = acc[0][0];
    #pragma unroll
    for (int nt = 0; nt < 4; ++nt)
      #pragma unroll
      for (int r = 0; r < 4; ++r) mx = fmaxf(mx, acc[nt][r]);
    mx = fmaxf(mx, __shfl_xor(mx, 16, 64));
    mx = fmaxf(mx, __shfl_xor(mx, 32, 64));
    float mn = fmaxf(mrow, mx);
    float alpha = __expf(mrow - mn);
    mrow = mn;
    float rs = 0.f;
    #pragma unroll
    for (int nt = 0; nt < 4; ++nt)
      #pragma unroll
      for (int r = 0; r < 4; ++r) {
        float p = __expf(acc[nt][r] - mn);
        acc[nt][r] = p; rs += p;
      }
    rs += __shfl_xor(rs, 16, 64);
    rs += __shfl_xor(rs, 32, 64);
    lrow = lrow * alpha + rs;

    // pack P to bf16 pairs: pk[nt][pp] = keys nt*16+quad*4+{2pp,2pp+1}
    unsigned pk[4][2];
    #pragma unroll
    for (int nt = 0; nt < 4; ++nt) {
      pk[nt][0] = packbf(acc[nt][0], acc[nt][1]);
      pk[nt][1] = packbf(acc[nt][2], acc[nt][3]);
    }

    // ---- rescale O (row = quad*4+r needs alpha of that qrow)
    #pragma unroll
    for (int r = 0; r < 4; ++r) {
      int src = (lane & 48) | (quad * 4 + r);
      float ar = __shfl(alpha, src, 64);
      #pragma unroll
      for (int dt = 0; dt < 8; ++dt) o[dt][r] *= ar;
    }

    // ---- P A-fragments via bpermute among the 4 lanes sharing l16
    bf16x8 pf[2];
    #pragma unroll
    for (int ks2 = 0; ks2 < 2; ++ks2) {
      int4v pd;
      #pragma unroll
      for (int jp = 0; jp < 4; ++jp) {
        int srcb = srcbase + 64 * (jp >> 1);  // src lane = l16+32(quad&1)+16(jp>>1)
        int v0 = __builtin_amdgcn_ds_bpermute(srcb, (int)pk[2 * ks2][jp & 1]);
        int v1 = __builtin_amdgcn_ds_bpermute(srcb, (int)pk[2 * ks2 + 1][jp & 1]);
        pd[jp] = hi2 ? v1 : v0;
      }
      pf[ks2] = __builtin_bit_cast(bf16x8, pd);
    }

    // ---- O += P V
    #pragma unroll
    for (int ks2 = 0; ks2 < 2; ++ks2) {
      #pragma unroll
      for (int dt = 0; dt < 8; ++dt) {
        int row = dt * 16 + l16;
        int f7 = (row ^ (row >> 3)) & 7;
        int bswz = (ks2 * 4 + quad) ^ f7;
        bf16x8 vf = *(const bf16x8*)(Vlds + row * 128 + bswz * 16);
        o[dt] = __builtin_amdgcn_mfma_f32_16x16x32_bf16(pf[ks2], vf, o[dt], 0, 0, 0);
      }
    }

    if (more) { __syncthreads(); stage_tiles(); }  // waits on prefetch loads here
  }

  // ---- epilogue: O / l  (l of row quad*4+r via shuffle)
  float linv[4];
  #pragma unroll
  for (int r = 0; r < 4; ++r) {
    int src = (lane & 48) | (quad * 4 + r);
    linv[r] = 1.0f / __shfl(lrow, src, 64);
  }
  float* ob = out + ((size_t)bh * Ss + qt * BM + wave * 16) * Dd;
  #pragma unroll
  for (int dt = 0; dt < 8; ++dt)
    #pragma unroll
    for (int r = 0; r < 4; ++r)
      ob[(quad * 4 + r) * Dd + dt * 16 + l16] = o[dt][r] * linv[r];
}

extern "C" void kernel_launch(void* const* d_in, const int* in_sizes, int n_in,
                              void* d_out, int out_size, void* d_ws, size_t ws_size,
                              hipStream_t stream) {
  const float* q = (const float*)d_in[0];
  const float* k = (const float*)d_in[1];
  const float* v = (const float*)d_in[2];
  float* out = (float*)d_out;
  dim3 grid(Bb * Hh * NQT);   // 1024
  dim3 block(256);
  hipLaunchKernelGGL(fa_fwd_kernel, grid, block, 0, stream, q, k, v, out);
}

// Round 3
// 205.024 us; speedup vs baseline: 2.3475x; 2.3475x over previous
//
#include <hip/hip_runtime.h>
#include <hip/hip_bf16.h>

// Causal flash attention fwd. B=2,H=16,S=2048,D=128, fp32 io, bf16 MFMA.
// R3: register prefetch WITHOUT address-taken arrays (R2's scratch bug),
// b128 staging writes, S^T softmax-along-regs + bpermute P transform.
constexpr int Bb = 2, Hh = 16, Ss = 2048, Dd = 128;
constexpr int BM = 64, BN = 64;
constexpr int NQT = Ss / BM;
constexpr float SCALE = 0.088388347648318447f;   // 1/sqrt(128)

typedef __attribute__((ext_vector_type(8))) short bf16x8;
typedef __attribute__((ext_vector_type(4))) float f32x4;
typedef __attribute__((ext_vector_type(4))) int int4v;

__device__ __forceinline__ unsigned bfbits(float f) {
  union { float f; unsigned u; } v; v.f = f;
  return v.u + 0x7FFFu + ((v.u >> 16) & 1u);     // RNE; bf16 = bits[31:16]
}
__device__ __forceinline__ short f2bf(float f) { return (short)(bfbits(f) >> 16); }
__device__ __forceinline__ unsigned packbf(float lo, float hi) {
  return (bfbits(lo) >> 16) | (bfbits(hi) & 0xFFFF0000u);
}
__device__ __forceinline__ float fcomp(float4 f, int j) {   // j is unroll-constant
  return j == 0 ? f.x : (j == 1 ? f.y : (j == 2 ? f.z : f.w));
}

__global__ __launch_bounds__(256, 2)
void fa_fwd_kernel(const float* __restrict__ q, const float* __restrict__ k,
                   const float* __restrict__ v, float* __restrict__ out) {
  // K tile row-major bf16: row=256B (16x16B blocks), block b at b^(row&15)
  __shared__ __align__(16) char Klds[BN * 256];    // 16 KB
  // V tile transposed Vt[d][key]: row=128B (8x16B blocks), block b at b^((d^(d>>3))&7)
  __shared__ __align__(16) char Vlds[Dd * 128];    // 16 KB

  const int tid = threadIdx.x;
  const int wave = tid >> 6, lane = tid & 63, quad = lane >> 4, l16 = lane & 15;
  const int bid = blockIdx.x;
  const int bh = bid & 31;
  const int qt = (NQT - 1) - (bid >> 5);           // heavy tiles first

  const float* qb = q + (size_t)bh * Ss * Dd;
  const float* kb = k + (size_t)bh * Ss * Dd;
  const float* vb = v + (size_t)bh * Ss * Dd;

  // ---- Q fragments (scale folded). Lane holds Q[qrow=wave*16+l16][d=32ks+8quad+j]
  bf16x8 qf[4];
  {
    const float* qr = qb + (size_t)(qt * BM + wave * 16 + l16) * Dd + quad * 8;
    #pragma unroll
    for (int ks = 0; ks < 4; ++ks) {
      float4 a = *(const float4*)(qr + ks * 32);
      float4 b = *(const float4*)(qr + ks * 32 + 4);
      bf16x8 t;
      t[0]=f2bf(a.x*SCALE); t[1]=f2bf(a.y*SCALE); t[2]=f2bf(a.z*SCALE); t[3]=f2bf(a.w*SCALE);
      t[4]=f2bf(b.x*SCALE); t[5]=f2bf(b.y*SCALE); t[6]=f2bf(b.z*SCALE); t[7]=f2bf(b.w*SCALE);
      qf[ks] = t;
    }
  }

  // ---- staging geometry (constant per thread)
  // K: thread owns 4 blocks: (row = krow0+16i, block kblk); loads 8 fp32, writes b128
  const int krow0 = tid >> 4;            // 0..15
  const int kblk  = tid & 15;            // block index = d/8
  const int kswz  = kblk ^ krow0;        // row&15 == krow0 for all i (row=krow0+16i)
  // V: thread owns 8keys x 4d micro-tile: kg = key-block, vdq*4 = d0
  const int vkg = tid >> 5;              // 0..7  (keys vkg*8 .. +7)
  const int vdq = tid & 31;              // d0 = vdq*4

  float4 ka[4], kc[4];                   // K prefetch: pair (ka[i],kc[i]) = 8 fp32
  float4 vr[8];                          // V prefetch: 8 key-rows x 4 d

  auto load_tiles = [&](int kt) {
    const float* Kg = kb + (size_t)(kt * BN) * Dd + kblk * 8;
    #pragma unroll
    for (int i = 0; i < 4; ++i) {
      ka[i] = *(const float4*)(Kg + (size_t)(krow0 + 16 * i) * Dd);
      kc[i] = *(const float4*)(Kg + (size_t)(krow0 + 16 * i) * Dd + 4);
    }
    const float* Vg = vb + (size_t)(kt * BN + vkg * 8) * Dd + vdq * 4;
    #pragma unroll
    for (int r = 0; r < 8; ++r)
      vr[r] = *(const float4*)(Vg + (size_t)r * Dd);
  };

  auto stage_tiles = [&]() {
    #pragma unroll
    for (int i = 0; i < 4; ++i) {
      bf16x8 t;
      t[0]=f2bf(ka[i].x); t[1]=f2bf(ka[i].y); t[2]=f2bf(ka[i].z); t[3]=f2bf(ka[i].w);
      t[4]=f2bf(kc[i].x); t[5]=f2bf(kc[i].y); t[6]=f2bf(kc[i].z); t[7]=f2bf(kc[i].w);
      *(bf16x8*)(Klds + (krow0 + 16 * i) * 256 + kswz * 16) = t;
    }
    #pragma unroll
    for (int j = 0; j < 4; ++j) {
      int d = vdq * 4 + j;
      int f7 = (d ^ (d >> 3)) & 7;
      bf16x8 t;
      #pragma unroll
      for (int r = 0; r < 8; ++r) t[r] = f2bf(fcomp(vr[r], j));
      *(bf16x8*)(Vlds + d * 128 + (vkg ^ f7) * 16) = t;
    }
  };

  f32x4 o[8];
  #pragma unroll
  for (int i = 0; i < 8; ++i) o[i] = (f32x4)(0.0f);
  float mrow = -3.0e38f, lrow = 0.0f;    // per-lane: qrow = wave*16 + l16

  load_tiles(0);
  stage_tiles();

  const int hi2 = quad >> 1;
  const int srcbase = (l16 + 32 * (quad & 1)) * 4;   // bpermute byte base

  for (int kt = 0; kt <= qt; ++kt) {
    __syncthreads();                     // tile kt visible
    const bool more = kt < qt;
    if (more) load_tiles(kt + 1);        // issue prefetch, no wait until loop end

    // ---- S^T = K Q^T : acc[nt][r] = S[qrow=l16][key=kt*64 + nt*16+quad*4+r]
    f32x4 acc[4];
    #pragma unroll
    for (int nt = 0; nt < 4; ++nt) acc[nt] = (f32x4)(0.0f);
    #pragma unroll
    for (int ks = 0; ks < 4; ++ks) {
      #pragma unroll
      for (int nt = 0; nt < 4; ++nt) {
        int row = nt * 16 + l16;
        int bswz = (ks * 4 + quad) ^ l16;
        bf16x8 kf = *(const bf16x8*)(Klds + row * 256 + bswz * 16);
        acc[nt] = __builtin_amdgcn_mfma_f32_16x16x32_bf16(kf, qf[ks], acc[nt], 0, 0, 0);
      }
    }

    // ---- causal mask on diagonal tile
    if (kt == qt) {
      #pragma unroll
      for (int nt = 0; nt < 4; ++nt)
        #pragma unroll
        for (int r = 0; r < 4; ++r)
          if (nt * 16 + quad * 4 + r > wave * 16 + l16) acc[nt][r] = -1.0e30f;
    }

    // ---- online softmax (row along regs; reduce over 4 lanes sharing l16)
    float mx = acc[0][0];
    #pragma unroll
    for (int nt = 0; nt < 4; ++nt)
      #pragma unroll
      for (int r = 0; r < 4; ++r) mx = fmaxf(mx, acc[nt][r]);
    mx = fmaxf(mx, __shfl_xor(mx, 16, 64));
    mx = fmaxf(mx, __shfl_xor(mx, 32, 64));
    float mn = fmaxf(mrow, mx);
    float alpha = __expf(mrow - mn);
    mrow = mn;
    float rs = 0.f;
    #pragma unroll
    for (int nt = 0; nt < 4; ++nt)
      #pragma unroll
      for (int r = 0; r < 4; ++r) {
        float p = __expf(acc[nt][r] - mn);
        acc[nt][r] = p; rs += p;
      }
    rs += __shfl_xor(rs, 16, 64);
    rs += __shfl_xor(rs, 32, 64);
    lrow = lrow * alpha + rs;

    // pack P: pk[nt][pp] = keys nt*16+quad*4+{2pp,2pp+1} (bf16 pair)
    unsigned pk0_0 = packbf(acc[0][0], acc[0][1]), pk0_1 = packbf(acc[0][2], acc[0][3]);
    unsigned pk1_0 = packbf(acc[1][0], acc[1][1]), pk1_1 = packbf(acc[1][2], acc[1][3]);
    unsigned pk2_0 = packbf(acc[2][0], acc[2][1]), pk2_1 = packbf(acc[2][2], acc[2][3]);
    unsigned pk3_0 = packbf(acc[3][0], acc[3][1]), pk3_1 = packbf(acc[3][2], acc[3][3]);

    // ---- rescale O (row quad*4+r needs alpha of that qrow)
    #pragma unroll
    for (int r = 0; r < 4; ++r) {
      int src = (lane & 48) | (quad * 4 + r);
      float ar = __shfl(alpha, src, 64);
      #pragma unroll
      for (int dt = 0; dt < 8; ++dt) o[dt][r] *= ar;
    }

    // ---- P A-fragments via bpermute among 4 lanes sharing l16
    bf16x8 pf[2];
    {
      int4v p0, p1;
      #pragma unroll
      for (int jp = 0; jp < 4; ++jp) {
        int srcb = srcbase + 64 * (jp >> 1);
        int a0 = __builtin_amdgcn_ds_bpermute(srcb, (int)((jp & 1) ? pk0_1 : pk0_0));
        int a1 = __builtin_amdgcn_ds_bpermute(srcb, (int)((jp & 1) ? pk1_1 : pk1_0));
        int a2 = __builtin_amdgcn_ds_bpermute(srcb, (int)((jp & 1) ? pk2_1 : pk2_0));
        int a3 = __builtin_amdgcn_ds_bpermute(srcb, (int)((jp & 1) ? pk3_1 : pk3_0));
        p0[jp] = hi2 ? a1 : a0;
        p1[jp] = hi2 ? a3 : a2;
      }
      pf[0] = __builtin_bit_cast(bf16x8, p0);
      pf[1] = __builtin_bit_cast(bf16x8, p1);
    }

    // ---- O += P V
    #pragma unroll
    for (int ks2 = 0; ks2 < 2; ++ks2) {
      #pragma unroll
      for (int dt = 0; dt < 8; ++dt) {
        int row = dt * 16 + l16;
        int f7 = (row ^ (row >> 3)) & 7;
        int bswz = (ks2 * 4 + quad) ^ f7;
        bf16x8 vf = *(const bf16x8*)(Vlds + row * 128 + bswz * 16);
        o[dt] = __builtin_amdgcn_mfma_f32_16x16x32_bf16(pf[ks2], vf, o[dt], 0, 0, 0);
      }
    }

    if (more) { __syncthreads(); stage_tiles(); }   // prefetch waits resolve here
  }

  // ---- epilogue: O / l
  float linv[4];
  #pragma unroll
  for (int r = 0; r < 4; ++r) {
    int src = (lane & 48) | (quad * 4 + r);
    linv[r] = 1.0f / __shfl(lrow, src, 64);
  }
  float* ob = out + ((size_t)bh * Ss + qt * BM + wave * 16) * Dd;
  #pragma unroll
  for (int dt = 0; dt < 8; ++dt)
    #pragma unroll
    for (int r = 0; r < 4; ++r)
      ob[(quad * 4 + r) * Dd + dt * 16 + l16] = o[dt][r] * linv[r];
}

extern "C" void kernel_launch(void* const* d_in, const int* in_sizes, int n_in,
                              void* d_out, int out_size, void* d_ws, size_t ws_size,
                              hipStream_t stream) {
  const float* q = (const float*)d_in[0];
  const float* k = (const float*)d_in[1];
  const float* v = (const float*)d_in[2];
  float* out = (float*)d_out;
  dim3 grid(Bb * Hh * NQT);   // 1024
  dim3 block(256);
  hipLaunchKernelGGL(fa_fwd_kernel, grid, block, 0, stream, q, k, v, out);
}